// Round 2
// 428.467 us; speedup vs baseline: 1.0148x; 1.0148x over previous
//
#include <hip/hip_runtime.h>

#define NN 8192
#define EE 262144
#define IN_DIM 512
#define HD1 256
#define HD2 128

typedef __attribute__((ext_vector_type(8))) short bf16x8;
typedef __attribute__((ext_vector_type(4))) float f32x4;

__device__ inline unsigned short f2bf(float f) {
    unsigned int u = __builtin_bit_cast(unsigned int, f);
    u += 0x7fffu + ((u >> 16) & 1u);
    return (unsigned short)(u >> 16);
}

// ---------------- graph preprocessing ----------------

__global__ void deg_kernel(const int* __restrict__ src, const int* __restrict__ dst,
                           int* __restrict__ deg_out, int* __restrict__ deg_in) {
    int e = blockIdx.x * blockDim.x + threadIdx.x;
    if (e < EE) {
        atomicAdd(&deg_out[src[e]], 1);
        atomicAdd(&deg_in[dst[e]], 1);
    }
}

__global__ void norm_kernel(const int* __restrict__ deg_out, const int* __restrict__ deg_in,
                            float* __restrict__ norm_src, float* __restrict__ norm_dst) {
    int i = blockIdx.x * blockDim.x + threadIdx.x;
    if (i < NN) {
        int dout = deg_out[i]; if (dout < 1) dout = 1;
        int din  = deg_in[i];  if (din  < 1) din  = 1;
        norm_src[i] = rsqrtf((float)dout);
        norm_dst[i] = rsqrtf((float)din);
    }
}

// exclusive prefix sum of 8192 counts -> row_start[8193]; single block, 256 threads
__global__ void scan_kernel(const int* __restrict__ counts, int* __restrict__ row_start) {
    __shared__ int sums[256];
    int t = threadIdx.x;
    int base = t * 32;
    int local[32];
    int s = 0;
    for (int i = 0; i < 32; i++) { local[i] = s; s += counts[base + i]; }
    sums[t] = s;
    __syncthreads();
    for (int off = 1; off < 256; off <<= 1) {
        int v = (t >= off) ? sums[t - off] : 0;
        __syncthreads();
        sums[t] += v;
        __syncthreads();
    }
    int coff = (t == 0) ? 0 : sums[t - 1];
    for (int i = 0; i < 32; i++) row_start[base + i] = coff + local[i];
    if (t == 255) row_start[NN] = sums[255];
}

__global__ void fill_kernel(const int* __restrict__ src, const int* __restrict__ dst,
                            const int* __restrict__ row_start, int* __restrict__ cursor,
                            int* __restrict__ eidx) {
    int e = blockIdx.x * blockDim.x + threadIdx.x;
    if (e < EE) {
        int d = dst[e];
        int pos = atomicAdd(&cursor[d], 1);
        eidx[row_start[d] + pos] = src[e];
    }
}

// ---------------- casts ----------------

__global__ void scale_cast_kernel(const float4* __restrict__ x, const float* __restrict__ norm_src,
                                  ushort4* __restrict__ out) {
    int idx = blockIdx.x * blockDim.x + threadIdx.x;  // over NN*IN_DIM/4
    if (idx < NN * IN_DIM / 4) {
        float ns = norm_src[idx >> 7];  // IN_DIM/4 = 128 float4 per row
        float4 v = x[idx];
        ushort4 o;
        o.x = f2bf(v.x * ns); o.y = f2bf(v.y * ns);
        o.z = f2bf(v.z * ns); o.w = f2bf(v.w * ns);
        out[idx] = o;
    }
}

__global__ void transpose_cast_kernel(const float* __restrict__ W, unsigned short* __restrict__ Wt,
                                      int K, int Nc) {
    int idx = blockIdx.x * blockDim.x + threadIdx.x;
    if (idx < K * Nc) {
        int n = idx / K;
        int k = idx - n * K;
        Wt[idx] = f2bf(W[k * Nc + n]);
    }
}

// ---------------- bf16 MFMA GEMM:  C[M][N] = A[M][K] * B[N][K]^T ----------------
// 128x128 tile per block, 4 waves (2x2) of 64x64, direct global fragment loads.
// Epilogue: stage 64-row half-tiles through LDS so stores are row-linear 16B/lane
// (512B-contiguous per 32 threads). EPI=0: plain fp32 store. EPI=1: sigmoid +
// nontemporal store (logits never re-read; keep them out of L2).
template <int EPI>
__global__ __launch_bounds__(256) void gemm_tn(const short* __restrict__ A,
                                               const short* __restrict__ B,
                                               float* __restrict__ C, int N, int K) {
    __shared__ float lds[64][132];   // +4 pad: write phase 2-way max (free)
    int wave = threadIdx.x >> 6;
    int lane = threadIdx.x & 63;
    int wr = wave >> 1, wc = wave & 1;
    int row0 = blockIdx.y * 128 + wr * 64;
    int col0 = blockIdx.x * 128 + wc * 64;
    int l15 = lane & 15, q = lane >> 4;

    f32x4 acc[4][4] = {};
    const short* Abase = A + (size_t)(row0 + l15) * K + q * 8;
    const short* Bbase = B + (size_t)(col0 + l15) * K + q * 8;
    int nk = K >> 5;
    for (int ks = 0; ks < nk; ks++) {
        bf16x8 a[4], b[4];
#pragma unroll
        for (int t = 0; t < 4; t++) {
            a[t] = *(const bf16x8*)(Abase + (size_t)t * 16 * K + ks * 32);
            b[t] = *(const bf16x8*)(Bbase + (size_t)t * 16 * K + ks * 32);
        }
#pragma unroll
        for (int ti = 0; ti < 4; ti++)
#pragma unroll
            for (int tj = 0; tj < 4; tj++)
                acc[ti][tj] = __builtin_amdgcn_mfma_f32_16x16x32_bf16(a[ti], b[tj], acc[ti][tj], 0, 0, 0);
    }

    // epilogue via LDS: two 64-row chunks (h = wr of the writing waves)
    int brow = blockIdx.y * 128;
    int bcol = blockIdx.x * 128;
#pragma unroll
    for (int h = 0; h < 2; h++) {
        __syncthreads();
        if (wr == h) {
#pragma unroll
            for (int ti = 0; ti < 4; ti++)
#pragma unroll
                for (int tj = 0; tj < 4; tj++)
#pragma unroll
                    for (int r = 0; r < 4; r++)
                        lds[ti * 16 + q * 4 + r][wc * 64 + tj * 16 + l15] = acc[ti][tj][r];
        }
        __syncthreads();
        // 64 rows x 128 cols = 2048 float4 / 256 threads = 8 each
#pragma unroll
        for (int it = 0; it < 8; it++) {
            int idx = it * 256 + threadIdx.x;
            int rl = idx >> 5;           // 0..63
            int c4 = (idx & 31) << 2;    // 0..124
            f32x4 v = *(const f32x4*)&lds[rl][c4];
            float* dst = C + (size_t)(brow + h * 64 + rl) * N + bcol + c4;
            if (EPI == 1) {
                f32x4 s;
                s[0] = __builtin_amdgcn_rcpf(1.0f + __expf(-v[0]));
                s[1] = __builtin_amdgcn_rcpf(1.0f + __expf(-v[1]));
                s[2] = __builtin_amdgcn_rcpf(1.0f + __expf(-v[2]));
                s[3] = __builtin_amdgcn_rcpf(1.0f + __expf(-v[3]));
                __builtin_nontemporal_store(s, (f32x4*)dst);
            } else {
                *(f32x4*)dst = v;
            }
        }
    }
}

// ---------------- SpMM (gather by CSR), wave-per-row ----------------

// x1n[r][t] = bf16( relu( (sum_{s in N(r)} h1[s][t]) * norm_dst[r] + b1[t] ) * norm_src[r] )
// one wave per row; lane owns 4 consecutive feature cols (float4 gathers, 1KB/inst)
__global__ __launch_bounds__(256) void spmm1_kernel(
        const float* __restrict__ h1, const int* __restrict__ row_start,
        const int* __restrict__ eidx, const float* __restrict__ norm_dst,
        const float* __restrict__ norm_src, const float* __restrict__ b1,
        unsigned short* __restrict__ x1n) {
    int wave = threadIdx.x >> 6, lane = threadIdx.x & 63;
    int r = blockIdx.x * 4 + wave;
    int s = row_start[r], e = row_start[r + 1];
    const float* hb = h1 + (size_t)lane * 4;
    float sx = 0.f, sy = 0.f, sz = 0.f, sw = 0.f;
    int i = s;
    for (; i + 4 <= e; i += 4) {
        int n0 = eidx[i], n1 = eidx[i + 1], n2 = eidx[i + 2], n3 = eidx[i + 3];
        float4 v0 = *(const float4*)(hb + (size_t)n0 * HD1);
        float4 v1 = *(const float4*)(hb + (size_t)n1 * HD1);
        float4 v2 = *(const float4*)(hb + (size_t)n2 * HD1);
        float4 v3 = *(const float4*)(hb + (size_t)n3 * HD1);
        sx += (v0.x + v1.x) + (v2.x + v3.x);
        sy += (v0.y + v1.y) + (v2.y + v3.y);
        sz += (v0.z + v1.z) + (v2.z + v3.z);
        sw += (v0.w + v1.w) + (v2.w + v3.w);
    }
    for (; i < e; i++) {
        float4 v = *(const float4*)(hb + (size_t)eidx[i] * HD1);
        sx += v.x; sy += v.y; sz += v.z; sw += v.w;
    }
    float nd = norm_dst[r], ns = norm_src[r];
    float4 bb = *(const float4*)(b1 + lane * 4);
    ushort4 o;
    o.x = f2bf(fmaxf(sx * nd + bb.x, 0.f) * ns);
    o.y = f2bf(fmaxf(sy * nd + bb.y, 0.f) * ns);
    o.z = f2bf(fmaxf(sz * nd + bb.z, 0.f) * ns);
    o.w = f2bf(fmaxf(sw * nd + bb.w, 0.f) * ns);
    *(ushort4*)(x1n + (size_t)r * HD1 + lane * 4) = o;
}

// emb[r][t] = sum * norm_dst[r] + b2[t]; fp32 to d_out + bf16 for decoder
// one wave per row; lane owns 2 feature cols (float2 gathers)
__global__ __launch_bounds__(256) void spmm2_kernel(
        const float* __restrict__ h2, const int* __restrict__ row_start,
        const int* __restrict__ eidx, const float* __restrict__ norm_dst,
        const float* __restrict__ b2, float* __restrict__ emb,
        unsigned short* __restrict__ embb) {
    int wave = threadIdx.x >> 6, lane = threadIdx.x & 63;
    int r = blockIdx.x * 4 + wave;
    int s = row_start[r], e = row_start[r + 1];
    const float* hb = h2 + (size_t)lane * 2;
    float sx = 0.f, sy = 0.f;
    int i = s;
    for (; i + 4 <= e; i += 4) {
        int n0 = eidx[i], n1 = eidx[i + 1], n2 = eidx[i + 2], n3 = eidx[i + 3];
        float2 v0 = *(const float2*)(hb + (size_t)n0 * HD2);
        float2 v1 = *(const float2*)(hb + (size_t)n1 * HD2);
        float2 v2 = *(const float2*)(hb + (size_t)n2 * HD2);
        float2 v3 = *(const float2*)(hb + (size_t)n3 * HD2);
        sx += (v0.x + v1.x) + (v2.x + v3.x);
        sy += (v0.y + v1.y) + (v2.y + v3.y);
    }
    for (; i < e; i++) {
        float2 v = *(const float2*)(hb + (size_t)eidx[i] * HD2);
        sx += v.x; sy += v.y;
    }
    float nd = norm_dst[r];
    float2 bb = *(const float2*)(b2 + lane * 2);
    float x0 = sx * nd + bb.x;
    float x1 = sy * nd + bb.y;
    float2 ov; ov.x = x0; ov.y = x1;
    *(float2*)(emb + (size_t)r * HD2 + lane * 2) = ov;
    ushort2 ob; ob.x = f2bf(x0); ob.y = f2bf(x1);
    *(ushort2*)(embb + (size_t)r * HD2 + lane * 2) = ob;
}

// ---------------- launch ----------------

extern "C" void kernel_launch(void* const* d_in, const int* in_sizes, int n_in,
                              void* d_out, int out_size, void* d_ws, size_t ws_size,
                              hipStream_t stream) {
    const float* features = (const float*)d_in[0];
    const int* src = (const int*)d_in[1];
    const int* dst = (const int*)d_in[2];
    const float* W1 = (const float*)d_in[3];
    const float* b1 = (const float*)d_in[4];
    const float* W2 = (const float*)d_in[5];
    const float* b2 = (const float*)d_in[6];

    char* ws = (char*)d_ws;
    size_t o = 0;
    auto alloc = [&](size_t bytes) -> char* {
        char* p = ws + o;
        o = (o + bytes + 255) & ~(size_t)255;
        return p;
    };
    int* deg_out = (int*)alloc(NN * 4);
    int* deg_in  = (int*)alloc(NN * 4);
    int* cursor  = (int*)alloc(NN * 4);   // contiguous with deg_* (32768 % 256 == 0)
    float* norm_src = (float*)alloc(NN * 4);
    float* norm_dst = (float*)alloc(NN * 4);
    int* row_start  = (int*)alloc((NN + 1) * 4);
    int* eidx       = (int*)alloc(EE * 4);
    unsigned short* xn  = (unsigned short*)alloc((size_t)NN * IN_DIM * 2);
    unsigned short* w1t = (unsigned short*)alloc((size_t)HD1 * IN_DIM * 2);
    unsigned short* w2t = (unsigned short*)alloc((size_t)HD2 * HD1 * 2);
    float* h1 = (float*)alloc((size_t)NN * HD1 * 4);
    unsigned short* x1n = (unsigned short*)alloc((size_t)NN * HD1 * 2);
    float* h2 = (float*)alloc((size_t)NN * HD2 * 4);
    unsigned short* embb = (unsigned short*)alloc((size_t)NN * HD2 * 2);

    float* emb_out = (float*)d_out;
    float* logits_out = emb_out + (size_t)NN * HD2;

    // zero deg_out, deg_in, cursor in one shot (contiguous)
    (void)hipMemsetAsync(deg_out, 0, (size_t)NN * 4 * 3, stream);

    deg_kernel<<<EE / 256, 256, 0, stream>>>(src, dst, deg_out, deg_in);
    norm_kernel<<<NN / 256, 256, 0, stream>>>(deg_out, deg_in, norm_src, norm_dst);
    scan_kernel<<<1, 256, 0, stream>>>(deg_in, row_start);
    fill_kernel<<<EE / 256, 256, 0, stream>>>(src, dst, row_start, cursor, eidx);

    scale_cast_kernel<<<(NN * IN_DIM / 4) / 256, 256, 0, stream>>>(
        (const float4*)features, norm_src, (ushort4*)xn);
    transpose_cast_kernel<<<(IN_DIM * HD1 + 255) / 256, 256, 0, stream>>>(W1, w1t, IN_DIM, HD1);
    transpose_cast_kernel<<<(HD1 * HD2 + 255) / 256, 256, 0, stream>>>(W2, w2t, HD1, HD2);

    // layer 1: h1 = xn @ W1
    gemm_tn<0><<<dim3(HD1 / 128, NN / 128), 256, 0, stream>>>(
        (const short*)xn, (const short*)w1t, h1, HD1, IN_DIM);
    spmm1_kernel<<<NN / 4, 256, 0, stream>>>(h1, row_start, eidx, norm_dst, norm_src, b1, x1n);

    // layer 2: h2 = x1n @ W2
    gemm_tn<0><<<dim3(HD2 / 128, NN / 128), 256, 0, stream>>>(
        (const short*)x1n, (const short*)w2t, h2, HD2, HD1);
    spmm2_kernel<<<NN / 4, 256, 0, stream>>>(h2, row_start, eidx, norm_dst, b2, emb_out, embb);

    // decoder: logits = sigmoid(emb @ emb^T)
    gemm_tn<1><<<dim3(NN / 128, NN / 128), 256, 0, stream>>>(
        (const short*)embb, (const short*)embb, logits_out, NN, HD2);
}

// Round 3
// 418.931 us; speedup vs baseline: 1.0379x; 1.0228x over previous
//
#include <hip/hip_runtime.h>

#define NN 8192
#define EE 262144
#define IN_DIM 512
#define HD1 256
#define HD2 128

typedef __attribute__((ext_vector_type(8))) short bf16x8;
typedef __attribute__((ext_vector_type(4))) float f32x4;

__device__ inline unsigned short f2bf(float f) {
    unsigned int u = __builtin_bit_cast(unsigned int, f);
    u += 0x7fffu + ((u >> 16) & 1u);
    return (unsigned short)(u >> 16);
}

// ---------------- fused prep: degree atomics + weight transpose-casts ----------------
// blocks [0,1024): edge degree atomics; [1024,1536): W1 transpose-cast; [1536,1664): W2.
__global__ void prep1_kernel(const int* __restrict__ src, const int* __restrict__ dst,
                             int* __restrict__ deg_out, int* __restrict__ deg_in,
                             const float* __restrict__ W1, unsigned short* __restrict__ w1t,
                             const float* __restrict__ W2, unsigned short* __restrict__ w2t) {
    int b = blockIdx.x;
    if (b < 1024) {
        int e = b * 256 + threadIdx.x;   // 1024*256 == EE exactly
        atomicAdd(&deg_out[src[e]], 1);
        atomicAdd(&deg_in[dst[e]], 1);
    } else if (b < 1536) {
        int idx = (b - 1024) * 256 + threadIdx.x;   // < IN_DIM*HD1 = 131072
        int n = idx / IN_DIM;
        int k = idx - n * IN_DIM;
        w1t[idx] = f2bf(W1[k * HD1 + n]);
    } else {
        int idx = (b - 1536) * 256 + threadIdx.x;   // < HD1*HD2 = 32768
        int n = idx / HD1;
        int k = idx - n * HD1;
        w2t[idx] = f2bf(W2[k * HD2 + n]);
    }
}

// ---------------- fused scan + norms: single block, 256 threads ----------------
// exclusive prefix sum of deg_in -> row_start[8193]; also rsqrt norms for both degrees.
__global__ void scan_norm_kernel(const int* __restrict__ deg_in, const int* __restrict__ deg_out,
                                 int* __restrict__ row_start,
                                 float* __restrict__ norm_src, float* __restrict__ norm_dst) {
    __shared__ int sums[256];
    int t = threadIdx.x;
    int base = t * 32;
    int local[32];
    int s = 0;
    for (int i = 0; i < 32; i++) {
        int c = deg_in[base + i];
        local[i] = s; s += c;
        int din = (c < 1) ? 1 : c;
        int dout = deg_out[base + i]; if (dout < 1) dout = 1;
        norm_dst[base + i] = rsqrtf((float)din);
        norm_src[base + i] = rsqrtf((float)dout);
    }
    sums[t] = s;
    __syncthreads();
    for (int off = 1; off < 256; off <<= 1) {
        int v = (t >= off) ? sums[t - off] : 0;
        __syncthreads();
        sums[t] += v;
        __syncthreads();
    }
    int coff = (t == 0) ? 0 : sums[t - 1];
    for (int i = 0; i < 32; i++) row_start[base + i] = coff + local[i];
    if (t == 255) row_start[NN] = sums[255];
}

__global__ void fill_kernel(const int* __restrict__ src, const int* __restrict__ dst,
                            const int* __restrict__ row_start, int* __restrict__ cursor,
                            int* __restrict__ eidx) {
    int e = blockIdx.x * blockDim.x + threadIdx.x;
    if (e < EE) {
        int d = dst[e];
        int pos = atomicAdd(&cursor[d], 1);
        eidx[row_start[d] + pos] = src[e];
    }
}

// ---------------- bf16 MFMA GEMM:  C[M][N] = A[M][K] * B[N][K]^T ----------------
// Tile: 32*TM rows x 128 cols, 4 waves (2x2); wave tile = 16*TM rows x 64 cols.
// TM=4: 128x128 tile (decoder); TM=2: 64x128 tile (doubles grid for small N).
// AF32=1: A is fp32, converted to bf16 in-register (removes separate cast kernel).
// EPI: 0=plain fp32 store, 1=sigmoid + nontemporal store, 2=row-scale by rowscale[].
template <int TM, int EPI, int AF32>
__global__ __launch_bounds__(256) void gemm_tn(const void* __restrict__ Av,
                                               const short* __restrict__ B,
                                               float* __restrict__ C,
                                               const float* __restrict__ rowscale,
                                               int N, int K) {
    __shared__ float lds[64][132];
    int wave = threadIdx.x >> 6;
    int lane = threadIdx.x & 63;
    int wr = wave >> 1, wc = wave & 1;
    int l15 = lane & 15, q = lane >> 4;
    int row0 = blockIdx.y * (32 * TM) + wr * (16 * TM);
    int col0 = blockIdx.x * 128 + wc * 64;

    f32x4 acc[TM][4] = {};
    const short* Ab = (const short*)Av + (size_t)(row0 + l15) * K + q * 8;
    const float* Af = (const float*)Av + (size_t)(row0 + l15) * K + q * 8;
    const short* Bb = B + (size_t)(col0 + l15) * K + q * 8;
    int nk = K >> 5;
    for (int ks = 0; ks < nk; ks++) {
        bf16x8 a[TM], b[4];
#pragma unroll
        for (int t = 0; t < TM; t++) {
            if (AF32) {
                f32x4 f0 = *(const f32x4*)(Af + (size_t)t * 16 * K + ks * 32);
                f32x4 f1 = *(const f32x4*)(Af + (size_t)t * 16 * K + ks * 32 + 4);
                bf16x8 av;
                av[0] = (short)f2bf(f0[0]); av[1] = (short)f2bf(f0[1]);
                av[2] = (short)f2bf(f0[2]); av[3] = (short)f2bf(f0[3]);
                av[4] = (short)f2bf(f1[0]); av[5] = (short)f2bf(f1[1]);
                av[6] = (short)f2bf(f1[2]); av[7] = (short)f2bf(f1[3]);
                a[t] = av;
            } else {
                a[t] = *(const bf16x8*)(Ab + (size_t)t * 16 * K + ks * 32);
            }
        }
#pragma unroll
        for (int t = 0; t < 4; t++)
            b[t] = *(const bf16x8*)(Bb + (size_t)t * 16 * K + ks * 32);
#pragma unroll
        for (int ti = 0; ti < TM; ti++)
#pragma unroll
            for (int tj = 0; tj < 4; tj++)
                acc[ti][tj] = __builtin_amdgcn_mfma_f32_16x16x32_bf16(a[ti], b[tj], acc[ti][tj], 0, 0, 0);
    }

    // epilogue via LDS: 64-row phases; stores are row-linear 16B/lane.
    int brow = blockIdx.y * (32 * TM);
    int bcol = blockIdx.x * 128;
    constexpr int PH = (32 * TM) / 64;   // 1 for TM=2, 2 for TM=4
#pragma unroll
    for (int h = 0; h < PH; h++) {
        __syncthreads();
        if (PH == 1 || wr == h) {
            int rbase = (PH == 1) ? wr * (16 * TM) : 0;
#pragma unroll
            for (int ti = 0; ti < TM; ti++)
#pragma unroll
                for (int tj = 0; tj < 4; tj++)
#pragma unroll
                    for (int r = 0; r < 4; r++)
                        lds[rbase + ti * 16 + q * 4 + r][wc * 64 + tj * 16 + l15] = acc[ti][tj][r];
        }
        __syncthreads();
        // 64 rows x 128 cols = 2048 f32x4 / 256 threads = 8 each
#pragma unroll
        for (int it = 0; it < 8; it++) {
            int idx = it * 256 + threadIdx.x;
            int rl = idx >> 5;           // 0..63
            int c4 = (idx & 31) << 2;    // 0..124
            f32x4 v = *(const f32x4*)&lds[rl][c4];
            int grow = brow + h * 64 + rl;
            float* dst = C + (size_t)grow * N + bcol + c4;
            if (EPI == 1) {
                f32x4 s;
                s[0] = __builtin_amdgcn_rcpf(1.0f + __expf(-v[0]));
                s[1] = __builtin_amdgcn_rcpf(1.0f + __expf(-v[1]));
                s[2] = __builtin_amdgcn_rcpf(1.0f + __expf(-v[2]));
                s[3] = __builtin_amdgcn_rcpf(1.0f + __expf(-v[3]));
                __builtin_nontemporal_store(s, (f32x4*)dst);
            } else if (EPI == 2) {
                float ns = rowscale[grow];
                v[0] *= ns; v[1] *= ns; v[2] *= ns; v[3] *= ns;
                *(f32x4*)dst = v;
            } else {
                *(f32x4*)dst = v;
            }
        }
    }
}

// ---------------- SpMM (gather by CSR), wave-per-row ----------------

__global__ __launch_bounds__(256) void spmm1_kernel(
        const float* __restrict__ h1, const int* __restrict__ row_start,
        const int* __restrict__ eidx, const float* __restrict__ norm_dst,
        const float* __restrict__ norm_src, const float* __restrict__ b1,
        unsigned short* __restrict__ x1n) {
    int wave = threadIdx.x >> 6, lane = threadIdx.x & 63;
    int r = blockIdx.x * 4 + wave;
    int s = row_start[r], e = row_start[r + 1];
    const float* hb = h1 + (size_t)lane * 4;
    float sx = 0.f, sy = 0.f, sz = 0.f, sw = 0.f;
    int i = s;
    for (; i + 4 <= e; i += 4) {
        int n0 = eidx[i], n1 = eidx[i + 1], n2 = eidx[i + 2], n3 = eidx[i + 3];
        float4 v0 = *(const float4*)(hb + (size_t)n0 * HD1);
        float4 v1 = *(const float4*)(hb + (size_t)n1 * HD1);
        float4 v2 = *(const float4*)(hb + (size_t)n2 * HD1);
        float4 v3 = *(const float4*)(hb + (size_t)n3 * HD1);
        sx += (v0.x + v1.x) + (v2.x + v3.x);
        sy += (v0.y + v1.y) + (v2.y + v3.y);
        sz += (v0.z + v1.z) + (v2.z + v3.z);
        sw += (v0.w + v1.w) + (v2.w + v3.w);
    }
    for (; i < e; i++) {
        float4 v = *(const float4*)(hb + (size_t)eidx[i] * HD1);
        sx += v.x; sy += v.y; sz += v.z; sw += v.w;
    }
    float nd = norm_dst[r], ns = norm_src[r];
    float4 bb = *(const float4*)(b1 + lane * 4);
    ushort4 o;
    o.x = f2bf(fmaxf(sx * nd + bb.x, 0.f) * ns);
    o.y = f2bf(fmaxf(sy * nd + bb.y, 0.f) * ns);
    o.z = f2bf(fmaxf(sz * nd + bb.z, 0.f) * ns);
    o.w = f2bf(fmaxf(sw * nd + bb.w, 0.f) * ns);
    *(ushort4*)(x1n + (size_t)r * HD1 + lane * 4) = o;
}

__global__ __launch_bounds__(256) void spmm2_kernel(
        const float* __restrict__ h2, const int* __restrict__ row_start,
        const int* __restrict__ eidx, const float* __restrict__ norm_dst,
        const float* __restrict__ b2, float* __restrict__ emb,
        unsigned short* __restrict__ embb) {
    int wave = threadIdx.x >> 6, lane = threadIdx.x & 63;
    int r = blockIdx.x * 4 + wave;
    int s = row_start[r], e = row_start[r + 1];
    const float* hb = h2 + (size_t)lane * 2;
    float sx = 0.f, sy = 0.f;
    int i = s;
    for (; i + 4 <= e; i += 4) {
        int n0 = eidx[i], n1 = eidx[i + 1], n2 = eidx[i + 2], n3 = eidx[i + 3];
        float2 v0 = *(const float2*)(hb + (size_t)n0 * HD2);
        float2 v1 = *(const float2*)(hb + (size_t)n1 * HD2);
        float2 v2 = *(const float2*)(hb + (size_t)n2 * HD2);
        float2 v3 = *(const float2*)(hb + (size_t)n3 * HD2);
        sx += (v0.x + v1.x) + (v2.x + v3.x);
        sy += (v0.y + v1.y) + (v2.y + v3.y);
    }
    for (; i < e; i++) {
        float2 v = *(const float2*)(hb + (size_t)eidx[i] * HD2);
        sx += v.x; sy += v.y;
    }
    float nd = norm_dst[r];
    float2 bb = *(const float2*)(b2 + lane * 2);
    float x0 = sx * nd + bb.x;
    float x1 = sy * nd + bb.y;
    float2 ov; ov.x = x0; ov.y = x1;
    *(float2*)(emb + (size_t)r * HD2 + lane * 2) = ov;
    ushort2 ob; ob.x = f2bf(x0); ob.y = f2bf(x1);
    *(ushort2*)(embb + (size_t)r * HD2 + lane * 2) = ob;
}

// ---------------- launch ----------------

extern "C" void kernel_launch(void* const* d_in, const int* in_sizes, int n_in,
                              void* d_out, int out_size, void* d_ws, size_t ws_size,
                              hipStream_t stream) {
    const float* features = (const float*)d_in[0];
    const int* src = (const int*)d_in[1];
    const int* dst = (const int*)d_in[2];
    const float* W1 = (const float*)d_in[3];
    const float* b1 = (const float*)d_in[4];
    const float* W2 = (const float*)d_in[5];
    const float* b2 = (const float*)d_in[6];

    char* ws = (char*)d_ws;
    size_t o = 0;
    auto alloc = [&](size_t bytes) -> char* {
        char* p = ws + o;
        o = (o + bytes + 255) & ~(size_t)255;
        return p;
    };
    int* deg_out = (int*)alloc(NN * 4);
    int* deg_in  = (int*)alloc(NN * 4);
    int* cursor  = (int*)alloc(NN * 4);   // contiguous with deg_* (32768 % 256 == 0)
    float* norm_src = (float*)alloc(NN * 4);
    float* norm_dst = (float*)alloc(NN * 4);
    int* row_start  = (int*)alloc((NN + 1) * 4);
    int* eidx       = (int*)alloc(EE * 4);
    unsigned short* w1t = (unsigned short*)alloc((size_t)HD1 * IN_DIM * 2);
    unsigned short* w2t = (unsigned short*)alloc((size_t)HD2 * HD1 * 2);
    float* h1 = (float*)alloc((size_t)NN * HD1 * 4);
    unsigned short* x1n = (unsigned short*)alloc((size_t)NN * HD1 * 2);
    float* h2 = (float*)alloc((size_t)NN * HD2 * 4);
    unsigned short* embb = (unsigned short*)alloc((size_t)NN * HD2 * 2);

    float* emb_out = (float*)d_out;
    float* logits_out = emb_out + (size_t)NN * HD2;

    // zero deg_out, deg_in, cursor in one shot (contiguous)
    (void)hipMemsetAsync(deg_out, 0, (size_t)NN * 4 * 3, stream);

    // degree atomics + both weight transpose-casts, one launch
    prep1_kernel<<<1664, 256, 0, stream>>>(src, dst, deg_out, deg_in, W1, w1t, W2, w2t);
    // prefix-sum + norms, one block
    scan_norm_kernel<<<1, 256, 0, stream>>>(deg_in, deg_out, row_start, norm_src, norm_dst);
    fill_kernel<<<EE / 256, 256, 0, stream>>>(src, dst, row_start, cursor, eidx);

    // layer 1: h1 = (features @ W1) * norm_src[row]   (fp32 A, in-register bf16 cvt)
    gemm_tn<2, 2, 1><<<dim3(HD1 / 128, NN / 64), 256, 0, stream>>>(
        (const void*)features, (const short*)w1t, h1, norm_src, HD1, IN_DIM);
    spmm1_kernel<<<NN / 4, 256, 0, stream>>>(h1, row_start, eidx, norm_dst, norm_src, b1, x1n);

    // layer 2: h2 = x1n @ W2
    gemm_tn<2, 0, 0><<<dim3(HD2 / 128, NN / 64), 256, 0, stream>>>(
        (const void*)x1n, (const short*)w2t, h2, nullptr, HD2, HD1);
    spmm2_kernel<<<NN / 4, 256, 0, stream>>>(h2, row_start, eidx, norm_dst, b2, emb_out, embb);

    // decoder: logits = sigmoid(emb @ emb^T)
    gemm_tn<4, 1, 0><<<dim3(NN / 128, NN / 128), 256, 0, stream>>>(
        (const void*)embb, (const short*)embb, logits_out, nullptr, NN, HD2);
}